// Round 7
// baseline (700.571 us; speedup 1.0000x reference)
//
#include <hip/hip_runtime.h>
#include <math.h>
#include <stdint.h>

// B=16, XL=YL=2048, D=1024. Plain-fp16 1-pass pipeline (fp32 accum):
//   proj : p = relu([x;y]16 @ W16^T + b)   K=1024  -> pHi fp16
//   score: sc = xp @ yp^T (+mask)          K=1024  -> fp32
//   soft : w = softmax(sc)                          -> fp16 (aliases pHi)
//   out  : out = w @ yT^T                  K=2048  -> fp32
// GEMM: 256x256 tile, BK=64 K-tiles, 8 waves (2x4), 2 LDS buffers (128KB),
// 8-phase schedule: per phase {ds_read subtile | stage 1 half-unit (2 gload_lds)
//  | s_barrier | lgkmcnt(0) | 16 MFMA (setprio) | s_barrier}, counted vmcnt(8)
// at kk boundaries only (never 0 mid-loop). Staging unit = (matrix, kk-half):
// unit for tile t lands 5-6 phases before use; buffer region freed one barrier
// before its overwrite (race-free by construction).
// LDS layout per kk-region (16KB): row r (0..255) x 4 slots of 16B,
// slot' = slot ^ (r&3)  -> conflict-floor ds_read_b128 and linear gload_lds dest
// with inverse-permuted global source (both-sides-or-neither rule).

typedef __attribute__((ext_vector_type(8))) _Float16 f16x8;
typedef __attribute__((ext_vector_type(4))) float f32x4;

__device__ __forceinline__ ushort h2u(_Float16 h) { return __builtin_bit_cast(ushort, h); }

__device__ __forceinline__ void ld16(const ushort* g, ushort* l) {
    __builtin_amdgcn_global_load_lds(
        (__attribute__((address_space(1))) void*)(g),
        (__attribute__((address_space(3))) void*)(l), 16, 0, 0);
}

#define BAR()   { __builtin_amdgcn_s_barrier(); asm volatile("" ::: "memory"); }
#define LGKM0() { asm volatile("s_waitcnt lgkmcnt(0)" ::: "memory"); __builtin_amdgcn_sched_barrier(0); }

// C = A @ B^T; A,B fp16 k-contiguous, K = T*64 over 2 virtual segments.
// EPI 0: fp32 C. EPI 1: relu(C+bias[n]) -> fp16 Chi. EPI 2: mask -> -inf, fp32.
template<int EPI>
__global__ __launch_bounds__(512) void gemm256(
    const ushort* __restrict__ A0, const ushort* __restrict__ A1, int sdA, size_t zsA,
    const ushort* __restrict__ B0, const ushort* __restrict__ B1, int sdB, size_t zsB,
    const float* __restrict__ bias, const int* __restrict__ mask, int zsMask,
    float* __restrict__ Cf, ushort* __restrict__ Chi, size_t zsC,
    int M, int N, int T)
{
    __shared__ char ldsb[131072];   // A [0,64K): buf(32K){kk(16K)}, B [64K,128K)

    // XCD-aware bijective block swizzle (all grids divisible by 8)
    const int gx = gridDim.x, gxy = gx * gridDim.y;
    const int total = gxy * gridDim.z;
    int hsw = blockIdx.z * gxy + blockIdx.y * gx + blockIdx.x;
    hsw = (hsw & 7) * (total >> 3) + (hsw >> 3);
    const int z = hsw / gxy;
    const int rem = hsw - z * gxy;
    const int by = rem / gx;
    const int bx = rem - by * gx;

    const int tid = threadIdx.x;
    const int lane = tid & 63;
    const int wv = tid >> 6, wm = wv >> 2, wn = wv & 3;
    const int m0 = by * 256, n0 = bx * 256;
    const int Th = T >> 1;

    A0 += (size_t)z * zsA; A1 += (size_t)z * zsA;
    B0 += (size_t)z * zsB; B1 += (size_t)z * zsB;

    // staging geometry: unit = 16KB = one (matrix, kk-half); 2 loads/thread.
    // dest linear: c*8192 + tid*16  -> row = c*128 + (tid>>2), slot' = tid&3
    // logical slot s = slot' ^ (row&3); global k = kk*32 + s*8
    const int srw = tid >> 2;                    // 0..127
    const int skslot = (tid & 3) ^ (srw & 3);    // logical k-slot

    auto stage_unit = [&](int g) {               // g = 4*tile + {0:Ak0,1:Bk0,2:Ak1,3:Bk1}
        const int tu = g >> 2, uu = g & 3;
        const int isB = uu & 1, kk = uu >> 1;
        const int seg = (tu >= Th);
        const int kof = (tu - (seg ? Th : 0)) * 64 + kk * 32 + skslot * 8;
        const ushort* src; int ld, rb;
        if (isB) { src = seg ? B1 : B0; ld = sdB; rb = n0; }
        else     { src = seg ? A1 : A0; ld = sdA; rb = m0; }
        const int dbase = isB * 65536 + (tu & 1) * 32768 + kk * 16384 + tid * 16;
        ld16(src + (size_t)(rb + srw) * ld + kof,       (ushort*)(ldsb + dbase));
        ld16(src + (size_t)(rb + 128 + srw) * ld + kof, (ushort*)(ldsb + dbase + 8192));
    };

    // compute-side read addresses (same swizzle): frag (m|n, kk), lane (fr,fq)
    const int fr = lane & 15, fq = lane >> 4;
    const int sl16 = (fq ^ (fr & 3)) << 4;
    const int aoff = (wm * 128 + fr) * 64 + sl16;
    const int boff = (wn * 64 + fr) * 64 + sl16;

    f32x4 acc[8][4];
    #pragma unroll
    for (int i = 0; i < 8; ++i)
        #pragma unroll
        for (int j = 0; j < 4; ++j)
            acc[i][j] = (f32x4){0.f, 0.f, 0.f, 0.f};

    f16x8 a[8], b0v, b1v;

#define LD_A(KK) { const char* p_ = ldsb + cur * 32768 + (KK) * 16384 + aoff;          \
    _Pragma("unroll") for (int m_ = 0; m_ < 8; ++m_) a[m_] = *(const f16x8*)(p_ + m_ * 1024); }
#define LD_B(KK, NP) { const char* p_ = ldsb + 65536 + cur * 32768 + (KK) * 16384 + boff + (NP) * 2048; \
    b0v = *(const f16x8*)(p_); b1v = *(const f16x8*)(p_ + 1024); }
#define MFMA16(NP) { __builtin_amdgcn_s_setprio(1);                                     \
    _Pragma("unroll") for (int m_ = 0; m_ < 8; ++m_) {                                  \
        acc[m_][2*(NP)]   = __builtin_amdgcn_mfma_f32_16x16x32_f16(a[m_], b0v, acc[m_][2*(NP)],   0,0,0); \
        acc[m_][2*(NP)+1] = __builtin_amdgcn_mfma_f32_16x16x32_f16(a[m_], b1v, acc[m_][2*(NP)+1], 0,0,0); } \
    __builtin_amdgcn_sched_barrier(0); __builtin_amdgcn_s_setprio(0); }

    // prologue: stage tile0 (4 units) + tile1 kk0 (2 units); wait tile0-kk0
    for (int g = 0; g < 6; ++g) stage_unit(g);
    asm volatile("s_waitcnt vmcnt(8)" ::: "memory");
    BAR();

    const int glim = 4 * T;
    for (int t = 0; t < T; ++t) {
        const int cur = t & 1;
        const int gb = 4 * t + 6;
        // phase 0: kk0, n-frags {0,1}
        LD_A(0); LD_B(0, 0);
        if (gb < glim) stage_unit(gb);
        BAR(); LGKM0(); MFMA16(0); BAR();
        // phase 1: kk0, n-frags {2,3}; guard this tile's kk1
        LD_B(0, 1);
        if (gb + 1 < glim) stage_unit(gb + 1);
        BAR(); LGKM0(); MFMA16(1);
        if (t < T - 1) { asm volatile("s_waitcnt vmcnt(8)" ::: "memory"); }
        else           { asm volatile("s_waitcnt vmcnt(0)" ::: "memory"); }
        BAR();
        // phase 2: kk1, n-frags {0,1}
        LD_A(1); LD_B(1, 0);
        if (gb + 2 < glim) stage_unit(gb + 2);
        BAR(); LGKM0(); MFMA16(0); BAR();
        // phase 3: kk1, n-frags {2,3}; guard next tile's kk0
        LD_B(1, 1);
        if (gb + 3 < glim) stage_unit(gb + 3);
        BAR(); LGKM0(); MFMA16(1);
        if (t < T - 2)       { asm volatile("s_waitcnt vmcnt(8)" ::: "memory"); }
        else if (t == T - 2) { asm volatile("s_waitcnt vmcnt(4)" ::: "memory"); }
        BAR();
    }

    // epilogue: within 16x16 frag, col = fr, row = fq*4 + r
    #pragma unroll
    for (int n = 0; n < 4; ++n) {
        const int col = n0 + wn * 64 + n * 16 + fr;
        float bb = 0.f;
        int mk = 0;
        if constexpr (EPI == 1) bb = bias[col];
        if constexpr (EPI == 2) mk = mask[(size_t)z * zsMask + col];
        #pragma unroll
        for (int m = 0; m < 8; ++m) {
            const int row = m0 + wm * 128 + m * 16 + fq * 4;
            #pragma unroll
            for (int r = 0; r < 4; ++r) {
                const float v = acc[m][n][r];
                const size_t idx = (size_t)z * zsC + (size_t)(row + r) * N + col;
                if constexpr (EPI == 0) {
                    Cf[idx] = v;
                } else if constexpr (EPI == 1) {
                    Chi[idx] = h2u((_Float16)fmaxf(v + bb, 0.f));
                } else {
                    Cf[idx] = mk ? -INFINITY : v;
                }
            }
        }
    }
#undef LD_A
#undef LD_B
#undef MFMA16
}

// fp32 -> fp16, 4 elems/thread, z-batched
__global__ __launch_bounds__(256) void cvt_f16(const float* __restrict__ in,
    ushort* __restrict__ o, size_t sIn4, size_t sOut)
{
    const size_t z = blockIdx.z;
    const int i = blockIdx.x * 256 + threadIdx.x;
    const float4 v = reinterpret_cast<const float4*>(in)[z * sIn4 + i];
    ushort4 h;
    h.x = h2u((_Float16)v.x); h.y = h2u((_Float16)v.y);
    h.z = h2u((_Float16)v.z); h.w = h2u((_Float16)v.w);
    reinterpret_cast<ushort4*>(o + z * sOut)[i] = h;
}

// y (2048x1024 fp32) -> fp16 rows (rH) + fp16 transpose (tT: 1024x2048)
__global__ __launch_bounds__(256) void cvt_transpose(const float* __restrict__ y,
    ushort* __restrict__ rH, ushort* __restrict__ tT,
    size_t sIn, size_t sR, size_t sT)
{
    __shared__ float tile[32][33];
    const size_t z = blockIdx.z;
    const int C = 1024, R = 2048;
    const float* yb = y + z * sIn;
    const int tx = threadIdx.x & 31, ty = threadIdx.x >> 5;
    const int c0 = blockIdx.x * 32, r0 = blockIdx.y * 32;
    #pragma unroll
    for (int k = 0; k < 4; ++k) {
        const int r = r0 + ty + k * 8;
        const float v = yb[(size_t)r * C + c0 + tx];
        tile[ty + k * 8][tx] = v;
        rH[z * sR + (size_t)r * C + c0 + tx] = h2u((_Float16)v);
    }
    __syncthreads();
    #pragma unroll
    for (int k = 0; k < 4; ++k) {
        const int c = c0 + ty + k * 8;
        tT[z * sT + (size_t)c * R + r0 + tx] = h2u((_Float16)tile[tx][ty + k * 8]);
    }
}

// row softmax over 2048 -> fp16; grid.x = G*2048 rows; float4 loads
__global__ __launch_bounds__(256) void softmax_f16(const float* __restrict__ S,
    ushort* __restrict__ Wout, size_t sS, size_t sW)
{
    const size_t row = blockIdx.x;
    const size_t b = row >> 11, r = row & 2047;
    const float4* p4 = reinterpret_cast<const float4*>(S + b * sS + r * 2048);
    ushort4* q4 = reinterpret_cast<ushort4*>(Wout + b * sW + r * 2048);
    const int tid = threadIdx.x;

    float4 v0 = p4[tid];
    float4 v1 = p4[tid + 256];
    float m = fmaxf(fmaxf(fmaxf(v0.x, v0.y), fmaxf(v0.z, v0.w)),
                    fmaxf(fmaxf(v1.x, v1.y), fmaxf(v1.z, v1.w)));
    #pragma unroll
    for (int off = 32; off >= 1; off >>= 1)
        m = fmaxf(m, __shfl_xor(m, off));

    __shared__ float redm[4], reds[4];
    if ((tid & 63) == 0) redm[tid >> 6] = m;
    __syncthreads();
    m = fmaxf(fmaxf(redm[0], redm[1]), fmaxf(redm[2], redm[3]));

    float e[8];
    e[0] = __expf(v0.x - m); e[1] = __expf(v0.y - m);
    e[2] = __expf(v0.z - m); e[3] = __expf(v0.w - m);
    e[4] = __expf(v1.x - m); e[5] = __expf(v1.y - m);
    e[6] = __expf(v1.z - m); e[7] = __expf(v1.w - m);
    float s = ((e[0] + e[1]) + (e[2] + e[3])) + ((e[4] + e[5]) + (e[6] + e[7]));
    #pragma unroll
    for (int off = 32; off >= 1; off >>= 1)
        s += __shfl_xor(s, off);
    if ((tid & 63) == 0) reds[tid >> 6] = s;
    __syncthreads();
    s = reds[0] + reds[1] + reds[2] + reds[3];

    const float inv = 1.f / s;
    ushort4 o0, o1;
    o0.x = h2u((_Float16)(e[0] * inv)); o0.y = h2u((_Float16)(e[1] * inv));
    o0.z = h2u((_Float16)(e[2] * inv)); o0.w = h2u((_Float16)(e[3] * inv));
    o1.x = h2u((_Float16)(e[4] * inv)); o1.y = h2u((_Float16)(e[5] * inv));
    o1.z = h2u((_Float16)(e[6] * inv)); o1.w = h2u((_Float16)(e[7] * inv));
    q4[tid] = o0;
    q4[tid + 256] = o1;
}

extern "C" void kernel_launch(void* const* d_in, const int* in_sizes, int n_in,
                              void* d_out, int out_size, void* d_ws, size_t ws_size,
                              hipStream_t stream)
{
    const float* x    = (const float*)d_in[0];  // (16, 2048, 1024)
    const float* y    = (const float*)d_in[1];  // (16, 2048, 1024)
    const int* ymask  = (const int*)d_in[2];    // (16, 2048)
    const float* W    = (const float*)d_in[3];  // (1024, 1024)
    const float* bias = (const float*)d_in[4];  // (1024,)
    float* out = (float*)d_out;

    const size_t BD = 2097152;                  // 2048*1024

    // per batch: R1 16MB (xyHi fp16 8MB; sc fp32 aliases all 16)
    //            R2 8MB pHi fp16 (w aliases after scores) | R3 4MB yT  => 28MB
    const size_t perBatch = 29360128ull;
    int G = 16;
    while (G > 1 && 2097152ull + (size_t)G * perBatch > ws_size) G >>= 1;

    uint8_t* wsb = (uint8_t*)d_ws;
    ushort* W16 = (ushort*)wsb;                          // 2 MB
    uint8_t* r1  = wsb + 2097152;                        // G * 16MB
    uint8_t* r2  = r1 + (size_t)G * 16777216;            // G * 8MB
    uint8_t* r3  = r2 + (size_t)G * 8388608;             // G * 4MB

    ushort* xyHi = (ushort*)r1;        // z-stride 8388608 ush
    float*  sc   = (float*)r1;         // z-stride 4194304 f32
    ushort* pHi  = (ushort*)r2;        // z-stride 4194304 ush; w aliases
    ushort* yT   = (ushort*)r3;        // z-stride 2097152 ush

    cvt_f16<<<dim3(1024, 1, 1), dim3(256), 0, stream>>>(W, W16, 0, 0);

    for (int bs = 0; bs < 16; bs += G) {
        const float* xg = x + (size_t)bs * BD;
        const float* yg = y + (size_t)bs * BD;

        cvt_f16<<<dim3(2048, 1, G), dim3(256), 0, stream>>>(
            xg, xyHi, BD / 4, 8388608);
        cvt_transpose<<<dim3(32, 64, G), dim3(256), 0, stream>>>(
            yg, xyHi + BD, yT, BD, 8388608, BD);

        // proj: M=4096, N=1024, K=1024 (T=16, segments at k=512)
        gemm256<1><<<dim3(4, 16, G), dim3(512), 0, stream>>>(
            xyHi, xyHi + 512, 1024, 8388608,
            W16, W16 + 512, 1024, 0,
            bias, nullptr, 0,
            nullptr, pHi, 4194304, 4096, 1024, 16);

        // scores: M=N=2048, K=1024 (T=16), masked
        gemm256<2><<<dim3(8, 8, G), dim3(512), 0, stream>>>(
            pHi, pHi + 512, 1024, 4194304,
            pHi + BD, pHi + BD + 512, 1024, 4194304,
            nullptr, ymask + (size_t)bs * 2048, 2048,
            sc, nullptr, 4194304, 2048, 2048, 16);

        softmax_f16<<<dim3(G * 2048), dim3(256), 0, stream>>>(
            sc, pHi, 4194304, 4194304);

        // out: M=2048, N=1024, K=2048 (T=32, segments at k=1024)
        gemm256<0><<<dim3(4, 8, G), dim3(512), 0, stream>>>(
            pHi, pHi + 1024, 2048, 4194304,
            yT, yT + 1024, 2048, 2097152,
            nullptr, nullptr, 0,
            out + (size_t)bs * BD, nullptr, BD, 2048, 1024, 32);
    }
}

// Round 8
// 668.578 us; speedup vs baseline: 1.0479x; 1.0479x over previous
//
#include <hip/hip_runtime.h>
#include <math.h>
#include <stdint.h>

// B=16, XL=YL=2048, D=1024. Plain-fp16 1-pass pipeline (fp32 accum):
//   proj : p = relu([x;y]16 @ W16^T + b)   K=1024  -> pHi fp16
//   score: sc = xp @ yp^T (+mask)          K=1024  -> fp32
//   soft : w = softmax(sc)                          -> fp16 (aliases pHi)
//   out  : out = w @ yT^T                  K=2048  -> fp32
// GEMM: 256x256 tile, BK=64 K-tiles, 8 waves (2x4), 2 LDS buffers (128KB),
// 8-phase schedule (4 phases per 64-K tile): per phase {ds_read subtile |
// stage 1 unit (2 gload_lds) | s_barrier | lgkmcnt(0) | 16 MFMA (setprio) |
// s_barrier}, counted vmcnt(8) at kk boundaries only (never 0 mid-loop).
// LDS kk-region (16KB) = 128 pair-rows x 128B, 8 slots of 16B:
//   logical slot s = (row&1)*4 + kq stored at s ^ (pair&7)
// -> measured-0-conflict layout (round 6), applied write-side via
// inverse-permuted global source + linear gload_lds dest, read-side via
// same XOR (both-sides-or-neither rule).

typedef __attribute__((ext_vector_type(8))) _Float16 f16x8;
typedef __attribute__((ext_vector_type(4))) float f32x4;

__device__ __forceinline__ ushort h2u(_Float16 h) { return __builtin_bit_cast(ushort, h); }

__device__ __forceinline__ void ld16(const ushort* g, ushort* l) {
    __builtin_amdgcn_global_load_lds(
        (__attribute__((address_space(1))) void*)(g),
        (__attribute__((address_space(3))) void*)(l), 16, 0, 0);
}

#define BAR()   { __builtin_amdgcn_s_barrier(); asm volatile("" ::: "memory"); }
#define LGKM0() { asm volatile("s_waitcnt lgkmcnt(0)" ::: "memory"); __builtin_amdgcn_sched_barrier(0); }

// C = A @ B^T; A,B fp16 k-contiguous, K = T*64 over 2 virtual segments.
// EPI 0: fp32 C. EPI 1: relu(C+bias[n]) -> fp16 Chi. EPI 2: mask -> -inf, fp32.
template<int EPI>
__global__ __launch_bounds__(512) void gemm256(
    const ushort* __restrict__ A0, const ushort* __restrict__ A1, int sdA, size_t zsA,
    const ushort* __restrict__ B0, const ushort* __restrict__ B1, int sdB, size_t zsB,
    const float* __restrict__ bias, const int* __restrict__ mask, int zsMask,
    float* __restrict__ Cf, ushort* __restrict__ Chi, size_t zsC,
    int M, int N, int T)
{
    __shared__ char ldsb[131072];   // A [0,64K): buf(32K){kk(16K)}, B [64K,128K)

    // XCD-aware bijective block swizzle (all grids divisible by 8)
    const int gx = gridDim.x, gxy = gx * gridDim.y;
    const int total = gxy * gridDim.z;
    int hsw = blockIdx.z * gxy + blockIdx.y * gx + blockIdx.x;
    hsw = (hsw & 7) * (total >> 3) + (hsw >> 3);
    const int z = hsw / gxy;
    const int rem = hsw - z * gxy;
    const int by = rem / gx;
    const int bx = rem - by * gx;

    const int tid = threadIdx.x;
    const int lane = tid & 63;
    const int wv = tid >> 6, wm = wv >> 2, wn = wv & 3;
    const int m0 = by * 256, n0 = bx * 256;
    const int Th = T >> 1;

    A0 += (size_t)z * zsA; A1 += (size_t)z * zsA;
    B0 += (size_t)z * zsB; B1 += (size_t)z * zsB;

    // staging geometry (pair-row swizzle): unit = 16KB kk-region, 2 loads/thread.
    // dest linear c*8192 + tid*16 -> pair = c*64 + (tid>>3), stored slot = tid&7;
    // logical slot s = (tid&7) ^ ((tid>>3)&7); row = c*128 + 2*(tid>>3) + (s>>2);
    // k elem = kk*32 + (s&3)*8.
    const int pl  = tid >> 3;               // local pair 0..63
    const int ss  = (tid & 7) ^ (pl & 7);   // logical slot
    const int sr0 = 2 * pl + (ss >> 2);     // row within chunk (0..127)
    const int ske = (ss & 3) * 8;           // k element offset (ushorts)

    auto stage_unit = [&](int g) {          // g = 4*tile + {0:Ak0,1:Bk0,2:Ak1,3:Bk1}
        const int tu = g >> 2, uu = g & 3;
        const int isB = uu & 1, kk = uu >> 1;
        const int seg = (tu >= Th);
        const int kof = (tu - (seg ? Th : 0)) * 64 + kk * 32 + ske;
        const ushort* src; int ld, rb;
        if (isB) { src = seg ? B1 : B0; ld = sdB; rb = n0; }
        else     { src = seg ? A1 : A0; ld = sdA; rb = m0; }
        const int dbase = isB * 65536 + (tu & 1) * 32768 + kk * 16384 + tid * 16;
        ld16(src + (size_t)(rb + sr0) * ld + kof,       (ushort*)(ldsb + dbase));
        ld16(src + (size_t)(rb + 128 + sr0) * ld + kof, (ushort*)(ldsb + dbase + 8192));
    };

    // compute-side read addresses (same swizzle): lane (fr,fq)
    // row = base + frag*16 + fr; pair&7 = (fr>>1)&7; s = (fr&1)*4 + fq
    const int fr = lane & 15, fq = lane >> 4;
    const int sl = (((fr & 1) << 2) | fq) ^ ((fr >> 1) & 7);
    const int aoff = (wm * 64 + (fr >> 1)) * 128 + sl * 16;   // + m*1024
    const int boff = (wn * 32 + (fr >> 1)) * 128 + sl * 16;   // + NP*2048

    f32x4 acc[8][4];
    #pragma unroll
    for (int i = 0; i < 8; ++i)
        #pragma unroll
        for (int j = 0; j < 4; ++j)
            acc[i][j] = (f32x4){0.f, 0.f, 0.f, 0.f};

    f16x8 a[8], b0v, b1v;

#define LD_A(KK) { const char* p_ = ldsb + cur * 32768 + (KK) * 16384 + aoff;          \
    _Pragma("unroll") for (int m_ = 0; m_ < 8; ++m_) a[m_] = *(const f16x8*)(p_ + m_ * 1024); }
#define LD_B(KK, NP) { const char* p_ = ldsb + 65536 + cur * 32768 + (KK) * 16384 + boff + (NP) * 2048; \
    b0v = *(const f16x8*)(p_); b1v = *(const f16x8*)(p_ + 1024); }
#define MFMA16(NP) { __builtin_amdgcn_s_setprio(1);                                     \
    _Pragma("unroll") for (int m_ = 0; m_ < 8; ++m_) {                                  \
        acc[m_][2*(NP)]   = __builtin_amdgcn_mfma_f32_16x16x32_f16(a[m_], b0v, acc[m_][2*(NP)],   0,0,0); \
        acc[m_][2*(NP)+1] = __builtin_amdgcn_mfma_f32_16x16x32_f16(a[m_], b1v, acc[m_][2*(NP)+1], 0,0,0); } \
    __builtin_amdgcn_s_setprio(0); }

    // prologue: stage tile0 (4 units) + tile1 kk0 (2 units); wait tile0-kk0
    for (int g = 0; g < 6; ++g) stage_unit(g);
    asm volatile("s_waitcnt vmcnt(8)" ::: "memory");
    BAR();

    const int glim = 4 * T;
    for (int t = 0; t < T; ++t) {
        const int cur = t & 1;
        const int gb = 4 * t + 6;
        // phase 0: kk0, n-frags {0,1}
        LD_A(0); LD_B(0, 0);
        if (gb < glim) stage_unit(gb);
        BAR(); LGKM0(); MFMA16(0); BAR();
        // phase 1: kk0, n-frags {2,3}; guard this tile's kk1
        LD_B(0, 1);
        if (gb + 1 < glim) stage_unit(gb + 1);
        BAR(); LGKM0(); MFMA16(1);
        if (t < T - 1) { asm volatile("s_waitcnt vmcnt(8)" ::: "memory"); }
        else           { asm volatile("s_waitcnt vmcnt(0)" ::: "memory"); }
        BAR();
        // phase 2: kk1, n-frags {0,1}
        LD_A(1); LD_B(1, 0);
        if (gb + 2 < glim) stage_unit(gb + 2);
        BAR(); LGKM0(); MFMA16(0); BAR();
        // phase 3: kk1, n-frags {2,3}; guard next tile's kk0
        LD_B(1, 1);
        if (gb + 3 < glim) stage_unit(gb + 3);
        BAR(); LGKM0(); MFMA16(1);
        if (t < T - 2)       { asm volatile("s_waitcnt vmcnt(8)" ::: "memory"); }
        else if (t == T - 2) { asm volatile("s_waitcnt vmcnt(4)" ::: "memory"); }
        BAR();
    }

    // epilogue: within 16x16 frag, col = fr, row = fq*4 + r
    #pragma unroll
    for (int n = 0; n < 4; ++n) {
        const int col = n0 + wn * 64 + n * 16 + fr;
        float bb = 0.f;
        int mk = 0;
        if constexpr (EPI == 1) bb = bias[col];
        if constexpr (EPI == 2) mk = mask[(size_t)z * zsMask + col];
        #pragma unroll
        for (int m = 0; m < 8; ++m) {
            const int row = m0 + wm * 128 + m * 16 + fq * 4;
            #pragma unroll
            for (int r = 0; r < 4; ++r) {
                const float v = acc[m][n][r];
                const size_t idx = (size_t)z * zsC + (size_t)(row + r) * N + col;
                if constexpr (EPI == 0) {
                    Cf[idx] = v;
                } else if constexpr (EPI == 1) {
                    Chi[idx] = h2u((_Float16)fmaxf(v + bb, 0.f));
                } else {
                    Cf[idx] = mk ? -INFINITY : v;
                }
            }
        }
    }
#undef LD_A
#undef LD_B
#undef MFMA16
}

// fp32 -> fp16, 4 elems/thread, z-batched
__global__ __launch_bounds__(256) void cvt_f16(const float* __restrict__ in,
    ushort* __restrict__ o, size_t sIn4, size_t sOut)
{
    const size_t z = blockIdx.z;
    const int i = blockIdx.x * 256 + threadIdx.x;
    const float4 v = reinterpret_cast<const float4*>(in)[z * sIn4 + i];
    ushort4 h;
    h.x = h2u((_Float16)v.x); h.y = h2u((_Float16)v.y);
    h.z = h2u((_Float16)v.z); h.w = h2u((_Float16)v.w);
    reinterpret_cast<ushort4*>(o + z * sOut)[i] = h;
}

// y (2048x1024 fp32) -> fp16 rows (rH) + fp16 transpose (tT: 1024x2048)
__global__ __launch_bounds__(256) void cvt_transpose(const float* __restrict__ y,
    ushort* __restrict__ rH, ushort* __restrict__ tT,
    size_t sIn, size_t sR, size_t sT)
{
    __shared__ float tile[32][33];
    const size_t z = blockIdx.z;
    const int C = 1024, R = 2048;
    const float* yb = y + z * sIn;
    const int tx = threadIdx.x & 31, ty = threadIdx.x >> 5;
    const int c0 = blockIdx.x * 32, r0 = blockIdx.y * 32;
    #pragma unroll
    for (int k = 0; k < 4; ++k) {
        const int r = r0 + ty + k * 8;
        const float v = yb[(size_t)r * C + c0 + tx];
        tile[ty + k * 8][tx] = v;
        rH[z * sR + (size_t)r * C + c0 + tx] = h2u((_Float16)v);
    }
    __syncthreads();
    #pragma unroll
    for (int k = 0; k < 4; ++k) {
        const int c = c0 + ty + k * 8;
        tT[z * sT + (size_t)c * R + r0 + tx] = h2u((_Float16)tile[tx][ty + k * 8]);
    }
}

// row softmax over 2048 -> fp16; grid.x = G*2048 rows; float4 loads
__global__ __launch_bounds__(256) void softmax_f16(const float* __restrict__ S,
    ushort* __restrict__ Wout, size_t sS, size_t sW)
{
    const size_t row = blockIdx.x;
    const size_t b = row >> 11, r = row & 2047;
    const float4* p4 = reinterpret_cast<const float4*>(S + b * sS + r * 2048);
    ushort4* q4 = reinterpret_cast<ushort4*>(Wout + b * sW + r * 2048);
    const int tid = threadIdx.x;

    float4 v0 = p4[tid];
    float4 v1 = p4[tid + 256];
    float m = fmaxf(fmaxf(fmaxf(v0.x, v0.y), fmaxf(v0.z, v0.w)),
                    fmaxf(fmaxf(v1.x, v1.y), fmaxf(v1.z, v1.w)));
    #pragma unroll
    for (int off = 32; off >= 1; off >>= 1)
        m = fmaxf(m, __shfl_xor(m, off));

    __shared__ float redm[4], reds[4];
    if ((tid & 63) == 0) redm[tid >> 6] = m;
    __syncthreads();
    m = fmaxf(fmaxf(redm[0], redm[1]), fmaxf(redm[2], redm[3]));

    float e[8];
    e[0] = __expf(v0.x - m); e[1] = __expf(v0.y - m);
    e[2] = __expf(v0.z - m); e[3] = __expf(v0.w - m);
    e[4] = __expf(v1.x - m); e[5] = __expf(v1.y - m);
    e[6] = __expf(v1.z - m); e[7] = __expf(v1.w - m);
    float s = ((e[0] + e[1]) + (e[2] + e[3])) + ((e[4] + e[5]) + (e[6] + e[7]));
    #pragma unroll
    for (int off = 32; off >= 1; off >>= 1)
        s += __shfl_xor(s, off);
    if ((tid & 63) == 0) reds[tid >> 6] = s;
    __syncthreads();
    s = reds[0] + reds[1] + reds[2] + reds[3];

    const float inv = 1.f / s;
    ushort4 o0, o1;
    o0.x = h2u((_Float16)(e[0] * inv)); o0.y = h2u((_Float16)(e[1] * inv));
    o0.z = h2u((_Float16)(e[2] * inv)); o0.w = h2u((_Float16)(e[3] * inv));
    o1.x = h2u((_Float16)(e[4] * inv)); o1.y = h2u((_Float16)(e[5] * inv));
    o1.z = h2u((_Float16)(e[6] * inv)); o1.w = h2u((_Float16)(e[7] * inv));
    q4[tid] = o0;
    q4[tid + 256] = o1;
}

extern "C" void kernel_launch(void* const* d_in, const int* in_sizes, int n_in,
                              void* d_out, int out_size, void* d_ws, size_t ws_size,
                              hipStream_t stream)
{
    const float* x    = (const float*)d_in[0];  // (16, 2048, 1024)
    const float* y    = (const float*)d_in[1];  // (16, 2048, 1024)
    const int* ymask  = (const int*)d_in[2];    // (16, 2048)
    const float* W    = (const float*)d_in[3];  // (1024, 1024)
    const float* bias = (const float*)d_in[4];  // (1024,)
    float* out = (float*)d_out;

    const size_t BD = 2097152;                  // 2048*1024

    // per batch: R1 16MB (xyHi fp16 8MB; sc fp32 aliases all 16)
    //            R2 8MB pHi fp16 (w aliases after scores) | R3 4MB yT  => 28MB
    const size_t perBatch = 29360128ull;
    int G = 16;
    while (G > 1 && 2097152ull + (size_t)G * perBatch > ws_size) G >>= 1;

    uint8_t* wsb = (uint8_t*)d_ws;
    ushort* W16 = (ushort*)wsb;                          // 2 MB
    uint8_t* r1  = wsb + 2097152;                        // G * 16MB
    uint8_t* r2  = r1 + (size_t)G * 16777216;            // G * 8MB
    uint8_t* r3  = r2 + (size_t)G * 8388608;             // G * 4MB

    ushort* xyHi = (ushort*)r1;        // z-stride 8388608 ush
    float*  sc   = (float*)r1;         // z-stride 4194304 f32
    ushort* pHi  = (ushort*)r2;        // z-stride 4194304 ush; w aliases
    ushort* yT   = (ushort*)r3;        // z-stride 2097152 ush

    cvt_f16<<<dim3(1024, 1, 1), dim3(256), 0, stream>>>(W, W16, 0, 0);

    for (int bs = 0; bs < 16; bs += G) {
        const float* xg = x + (size_t)bs * BD;
        const float* yg = y + (size_t)bs * BD;

        cvt_f16<<<dim3(2048, 1, G), dim3(256), 0, stream>>>(
            xg, xyHi, BD / 4, 8388608);
        cvt_transpose<<<dim3(32, 64, G), dim3(256), 0, stream>>>(
            yg, xyHi + BD, yT, BD, 8388608, BD);

        // proj: M=4096, N=1024, K=1024 (T=16, segments at k=512)
        gemm256<1><<<dim3(4, 16, G), dim3(512), 0, stream>>>(
            xyHi, xyHi + 512, 1024, 8388608,
            W16, W16 + 512, 1024, 0,
            bias, nullptr, 0,
            nullptr, pHi, 4194304, 4096, 1024, 16);

        // scores: M=N=2048, K=1024 (T=16), masked
        gemm256<2><<<dim3(8, 8, G), dim3(512), 0, stream>>>(
            pHi, pHi + 512, 1024, 4194304,
            pHi + BD, pHi + BD + 512, 1024, 4194304,
            nullptr, ymask + (size_t)bs * 2048, 2048,
            sc, nullptr, 4194304, 2048, 2048, 16);

        softmax_f16<<<dim3(G * 2048), dim3(256), 0, stream>>>(
            sc, pHi, 4194304, 4194304);

        // out: M=2048, N=1024, K=2048 (T=32, segments at k=1024)
        gemm256<0><<<dim3(4, 8, G), dim3(512), 0, stream>>>(
            pHi, pHi + 1024, 2048, 4194304,
            yT, yT + 1024, 2048, 2097152,
            nullptr, nullptr, 0,
            out + (size_t)bs * BD, nullptr, BD, 2048, 1024, 32);
    }
}

// Round 9
// 638.187 us; speedup vs baseline: 1.0978x; 1.0476x over previous
//
#include <hip/hip_runtime.h>
#include <math.h>
#include <stdint.h>

// B=16, XL=YL=2048, D=1024. Plain-fp16 1-pass pipeline (fp32 accum):
//   proj : p = relu([x;y]16 @ W16^T + b)   K=1024  -> pHi fp16
//   score: sc = xp @ yp^T (+mask)          K=1024  -> fp32
//   soft : w = softmax(sc)                          -> fp16 (aliases pHi)
//   out  : out = w @ yT^T                  K=2048  -> fp32
// GEMM: 256x256 tile, contiguous K = T*64, 8 waves (2x4), 2 LDS buffers (128KB),
// 8-phase/2-tile schedule, fully unrolled: all LDS offsets are immediates,
// staging via 4 running global pointers (+128 elems per 2-tile iter, static
// +96/+128/+160/+192 unit offsets). Counted vmcnt(8) twice per tile (never 0
// mid-loop). LDS kk-region (16KB) = 128 pair-rows x 128B, 8 slots of 16B,
// slot stored at s ^ (pair&7) — measured-0-conflict layout (rounds 6/8),
// write-side via inverse-permuted global source + linear gload_lds dest.

typedef __attribute__((ext_vector_type(8))) _Float16 f16x8;
typedef __attribute__((ext_vector_type(4))) float f32x4;

__device__ __forceinline__ ushort h2u(_Float16 h) { return __builtin_bit_cast(ushort, h); }

__device__ __forceinline__ void ld16(const ushort* g, ushort* l) {
    __builtin_amdgcn_global_load_lds(
        (__attribute__((address_space(1))) void*)(g),
        (__attribute__((address_space(3))) void*)(l), 16, 0, 0);
}

#define BAR()   { __builtin_amdgcn_s_barrier(); asm volatile("" ::: "memory"); }
#define LGKM0() { asm volatile("s_waitcnt lgkmcnt(0)" ::: "memory"); __builtin_amdgcn_sched_barrier(0); }
#define VMW(N)  asm volatile("s_waitcnt vmcnt(" #N ")" ::: "memory");

// C = A @ B^T; A: (rows x K), B: (rows x K), k-contiguous, K = T*64 = sdA = sdB.
// EPI 0: fp32 C. EPI 1: relu(C+bias[n]) -> fp16 Chi. EPI 2: mask -> -inf, fp32.
template<int EPI>
__global__ __launch_bounds__(512) void gemm256(
    const ushort* __restrict__ A, size_t zsA,
    const ushort* __restrict__ B, size_t zsB,
    const float* __restrict__ bias, const int* __restrict__ mask, int zsMask,
    float* __restrict__ Cf, ushort* __restrict__ Chi, size_t zsC,
    int sdA, int sdB, int N, int T)
{
    __shared__ char ldsb[131072];   // A [0,64K): buf(32K){kk(16K)}, B [64K,128K)

    // XCD-aware bijective block swizzle (all grids divisible by 8)
    const int gx = gridDim.x, gxy = gx * gridDim.y;
    const int total = gxy * gridDim.z;
    int hsw = blockIdx.z * gxy + blockIdx.y * gx + blockIdx.x;
    hsw = (hsw & 7) * (total >> 3) + (hsw >> 3);
    const int z = hsw / gxy;
    const int rem = hsw - z * gxy;
    const int by = rem / gx;
    const int bx = rem - by * gx;

    const int tid = threadIdx.x;
    const int lane = tid & 63;
    const int wv = tid >> 6, wm = wv >> 2, wn = wv & 3;
    const int m0 = by * 256, n0 = bx * 256;

    // staging geometry (pair-row swizzle): dest linear tid*16 within kk-region;
    // pair = tid>>3, stored slot = tid&7; logical slot s = (tid&7)^((tid>>3)&7);
    // row = 2*(tid>>3)+(s>>2); k elem = (s&3)*8.
    const int pl  = tid >> 3;
    const int ss  = (tid & 7) ^ (pl & 7);
    const int sr0 = 2 * pl + (ss >> 2);
    const int ske = (ss & 3) * 8;
    const int tb  = tid * 16;

    const ushort* gA0 = A + (size_t)z * zsA + (size_t)(m0 + sr0) * sdA + ske;
    const ushort* gA1 = A + (size_t)z * zsA + (size_t)(m0 + 128 + sr0) * sdA + ske;
    const ushort* gB0 = B + (size_t)z * zsB + (size_t)(n0 + sr0) * sdB + ske;
    const ushort* gB1 = B + (size_t)z * zsB + (size_t)(n0 + 128 + sr0) * sdB + ske;

#define ST_A(KOF, DOF) { ld16(gA0 + (KOF), (ushort*)(ldsb + (DOF) + tb));          \
                         ld16(gA1 + (KOF), (ushort*)(ldsb + (DOF) + 8192 + tb)); }
#define ST_B(KOF, DOF) { ld16(gB0 + (KOF), (ushort*)(ldsb + 65536 + (DOF) + tb));  \
                         ld16(gB1 + (KOF), (ushort*)(ldsb + 65536 + (DOF) + 8192 + tb)); }

    // compute-side read addresses (same swizzle): lane (fr,fq)
    const int fr = lane & 15, fq = lane >> 4;
    const int sl = (((fr & 1) << 2) | fq) ^ ((fr >> 1) & 7);
    const int aoff = (wm * 64 + (fr >> 1)) * 128 + sl * 16;   // + m*1024
    const int boff = (wn * 32 + (fr >> 1)) * 128 + sl * 16;   // + n*1024

    f32x4 acc[8][4];
    #pragma unroll
    for (int i = 0; i < 8; ++i)
        #pragma unroll
        for (int j = 0; j < 4; ++j)
            acc[i][j] = (f32x4){0.f, 0.f, 0.f, 0.f};

    f16x8 a[4], b[4];

#define RD_B(DOF) { const char* p_ = ldsb + 65536 + (DOF) + boff;                  \
    b[0] = *(const f16x8*)(p_);        b[1] = *(const f16x8*)(p_ + 1024);          \
    b[2] = *(const f16x8*)(p_ + 2048); b[3] = *(const f16x8*)(p_ + 3072); }
#define RD_AL(DOF) { const char* p_ = ldsb + (DOF) + aoff;                         \
    a[0] = *(const f16x8*)(p_);        a[1] = *(const f16x8*)(p_ + 1024);          \
    a[2] = *(const f16x8*)(p_ + 2048); a[3] = *(const f16x8*)(p_ + 3072); }
#define RD_AH(DOF) { const char* p_ = ldsb + (DOF) + aoff + 4096;                  \
    a[0] = *(const f16x8*)(p_);        a[1] = *(const f16x8*)(p_ + 1024);          \
    a[2] = *(const f16x8*)(p_ + 2048); a[3] = *(const f16x8*)(p_ + 3072); }
#define MF_L { __builtin_amdgcn_s_setprio(1);                                      \
    _Pragma("unroll") for (int m_ = 0; m_ < 4; ++m_)                               \
        _Pragma("unroll") for (int n_ = 0; n_ < 4; ++n_)                           \
            acc[m_][n_] = __builtin_amdgcn_mfma_f32_16x16x32_f16(a[m_], b[n_], acc[m_][n_], 0, 0, 0); \
    __builtin_amdgcn_s_setprio(0); }
#define MF_H { __builtin_amdgcn_s_setprio(1);                                      \
    _Pragma("unroll") for (int m_ = 0; m_ < 4; ++m_)                               \
        _Pragma("unroll") for (int n_ = 0; n_ < 4; ++n_)                           \
            acc[m_ + 4][n_] = __builtin_amdgcn_mfma_f32_16x16x32_f16(a[m_], b[n_], acc[m_ + 4][n_], 0, 0, 0); \
    __builtin_amdgcn_s_setprio(0); }

// One tile = 4 phases: {B+A_lo reads | stage | bar | lgkm0 | 16 MFMA | bar} x
// {kk0-L, kk0-H, kk1-L, kk1-H}. S0..S3 = stage units, W1/W3 = vmcnt waits.
#define TILE(BUF, S0, S1, S2, S3, W1, W3)                                          \
    RD_B((BUF)*32768); RD_AL((BUF)*32768);                                         \
    S0; BAR(); LGKM0(); MF_L; BAR();                                               \
    RD_AH((BUF)*32768);                                                            \
    S1; BAR(); LGKM0(); MF_H; W1; BAR();                                           \
    RD_B((BUF)*32768 + 16384); RD_AL((BUF)*32768 + 16384);                         \
    S2; BAR(); LGKM0(); MF_L; BAR();                                               \
    RD_AH((BUF)*32768 + 16384);                                                    \
    S3; BAR(); LGKM0(); MF_H; W3; BAR();

    // prologue: tile0 all 4 units + tile1 kk0 units (12 loads); wait tile0-kk0
    ST_A(0, 0);      ST_B(0, 0);
    ST_A(32, 16384); ST_B(32, 16384);
    ST_A(64, 32768); ST_B(64, 32768);
    VMW(8);
    BAR();

    // main: 2 tiles per iteration; stages cover (t+1,kk1),(t+2,kk0),(t+2,kk1),(t+3,kk0)
    for (int it = 0; it < (T - 2) / 2; ++it) {
        TILE(0, ST_A(96, 49152),  ST_B(96, 49152),  ST_A(128, 0),     ST_B(128, 0),     VMW(8), VMW(8))
        TILE(1, ST_A(160, 16384), ST_B(160, 16384), ST_A(192, 32768), ST_B(192, 32768), VMW(8), VMW(8))
        gA0 += 128; gA1 += 128; gB0 += 128; gB1 += 128;
    }
    // tail: tile T-2 (stages (T-1,kk1) only), tile T-1 (drain)
    TILE(0, ST_A(96, 49152), ST_B(96, 49152), , , VMW(8), VMW(4))
    TILE(1, , , , , VMW(0), )

    // epilogue: within 16x16 frag, col = fr, row = fq*4 + r
    #pragma unroll
    for (int n = 0; n < 4; ++n) {
        const int col = n0 + wn * 64 + n * 16 + fr;
        float bb = 0.f;
        int mk = 0;
        if constexpr (EPI == 1) bb = bias[col];
        if constexpr (EPI == 2) mk = mask[(size_t)z * zsMask + col];
        #pragma unroll
        for (int m = 0; m < 8; ++m) {
            const int row = m0 + wm * 128 + m * 16 + fq * 4;
            #pragma unroll
            for (int r = 0; r < 4; ++r) {
                const float v = acc[m][n][r];
                const size_t idx = (size_t)z * zsC + (size_t)(row + r) * N + col;
                if constexpr (EPI == 0) {
                    Cf[idx] = v;
                } else if constexpr (EPI == 1) {
                    Chi[idx] = h2u((_Float16)fmaxf(v + bb, 0.f));
                } else {
                    Cf[idx] = mk ? -INFINITY : v;
                }
            }
        }
    }
#undef ST_A
#undef ST_B
#undef RD_B
#undef RD_AL
#undef RD_AH
#undef MF_L
#undef MF_H
#undef TILE
}

// fp32 -> fp16, 4 elems/thread, z-batched
__global__ __launch_bounds__(256) void cvt_f16(const float* __restrict__ in,
    ushort* __restrict__ o, size_t sIn4, size_t sOut)
{
    const size_t z = blockIdx.z;
    const int i = blockIdx.x * 256 + threadIdx.x;
    const float4 v = reinterpret_cast<const float4*>(in)[z * sIn4 + i];
    ushort4 h;
    h.x = h2u((_Float16)v.x); h.y = h2u((_Float16)v.y);
    h.z = h2u((_Float16)v.z); h.w = h2u((_Float16)v.w);
    reinterpret_cast<ushort4*>(o + z * sOut)[i] = h;
}

// y (2048x1024 fp32) -> fp16 rows (rH) + fp16 transpose (tT: 1024x2048)
__global__ __launch_bounds__(256) void cvt_transpose(const float* __restrict__ y,
    ushort* __restrict__ rH, ushort* __restrict__ tT,
    size_t sIn, size_t sR, size_t sT)
{
    __shared__ float tile[32][33];
    const size_t z = blockIdx.z;
    const int C = 1024, R = 2048;
    const float* yb = y + z * sIn;
    const int tx = threadIdx.x & 31, ty = threadIdx.x >> 5;
    const int c0 = blockIdx.x * 32, r0 = blockIdx.y * 32;
    #pragma unroll
    for (int k = 0; k < 4; ++k) {
        const int r = r0 + ty + k * 8;
        const float v = yb[(size_t)r * C + c0 + tx];
        tile[ty + k * 8][tx] = v;
        rH[z * sR + (size_t)r * C + c0 + tx] = h2u((_Float16)v);
    }
    __syncthreads();
    #pragma unroll
    for (int k = 0; k < 4; ++k) {
        const int c = c0 + ty + k * 8;
        tT[z * sT + (size_t)c * R + r0 + tx] = h2u((_Float16)tile[tx][ty + k * 8]);
    }
}

// row softmax over 2048 -> fp16; grid.x = G*2048 rows; float4 loads
__global__ __launch_bounds__(256) void softmax_f16(const float* __restrict__ S,
    ushort* __restrict__ Wout, size_t sS, size_t sW)
{
    const size_t row = blockIdx.x;
    const size_t b = row >> 11, r = row & 2047;
    const float4* p4 = reinterpret_cast<const float4*>(S + b * sS + r * 2048);
    ushort4* q4 = reinterpret_cast<ushort4*>(Wout + b * sW + r * 2048);
    const int tid = threadIdx.x;

    float4 v0 = p4[tid];
    float4 v1 = p4[tid + 256];
    float m = fmaxf(fmaxf(fmaxf(v0.x, v0.y), fmaxf(v0.z, v0.w)),
                    fmaxf(fmaxf(v1.x, v1.y), fmaxf(v1.z, v1.w)));
    #pragma unroll
    for (int off = 32; off >= 1; off >>= 1)
        m = fmaxf(m, __shfl_xor(m, off));

    __shared__ float redm[4], reds[4];
    if ((tid & 63) == 0) redm[tid >> 6] = m;
    __syncthreads();
    m = fmaxf(fmaxf(redm[0], redm[1]), fmaxf(redm[2], redm[3]));

    float e[8];
    e[0] = __expf(v0.x - m); e[1] = __expf(v0.y - m);
    e[2] = __expf(v0.z - m); e[3] = __expf(v0.w - m);
    e[4] = __expf(v1.x - m); e[5] = __expf(v1.y - m);
    e[6] = __expf(v1.z - m); e[7] = __expf(v1.w - m);
    float s = ((e[0] + e[1]) + (e[2] + e[3])) + ((e[4] + e[5]) + (e[6] + e[7]));
    #pragma unroll
    for (int off = 32; off >= 1; off >>= 1)
        s += __shfl_xor(s, off);
    if ((tid & 63) == 0) reds[tid >> 6] = s;
    __syncthreads();
    s = reds[0] + reds[1] + reds[2] + reds[3];

    const float inv = 1.f / s;
    ushort4 o0, o1;
    o0.x = h2u((_Float16)(e[0] * inv)); o0.y = h2u((_Float16)(e[1] * inv));
    o0.z = h2u((_Float16)(e[2] * inv)); o0.w = h2u((_Float16)(e[3] * inv));
    o1.x = h2u((_Float16)(e[4] * inv)); o1.y = h2u((_Float16)(e[5] * inv));
    o1.z = h2u((_Float16)(e[6] * inv)); o1.w = h2u((_Float16)(e[7] * inv));
    q4[tid] = o0;
    q4[tid + 256] = o1;
}

extern "C" void kernel_launch(void* const* d_in, const int* in_sizes, int n_in,
                              void* d_out, int out_size, void* d_ws, size_t ws_size,
                              hipStream_t stream)
{
    const float* x    = (const float*)d_in[0];  // (16, 2048, 1024)
    const float* y    = (const float*)d_in[1];  // (16, 2048, 1024)
    const int* ymask  = (const int*)d_in[2];    // (16, 2048)
    const float* W    = (const float*)d_in[3];  // (1024, 1024)
    const float* bias = (const float*)d_in[4];  // (1024,)
    float* out = (float*)d_out;

    const size_t BD = 2097152;                  // 2048*1024

    // per batch: R1 16MB (xyHi fp16 8MB; sc fp32 aliases all 16)
    //            R2 8MB pHi fp16 (w aliases after scores) | R3 4MB yT  => 28MB
    const size_t perBatch = 29360128ull;
    int G = 16;
    while (G > 1 && 2097152ull + (size_t)G * perBatch > ws_size) G >>= 1;

    uint8_t* wsb = (uint8_t*)d_ws;
    ushort* W16 = (ushort*)wsb;                          // 2 MB
    uint8_t* r1  = wsb + 2097152;                        // G * 16MB
    uint8_t* r2  = r1 + (size_t)G * 16777216;            // G * 8MB
    uint8_t* r3  = r2 + (size_t)G * 8388608;             // G * 4MB

    ushort* xyHi = (ushort*)r1;        // z-stride 8388608 ush
    float*  sc   = (float*)r1;         // z-stride 4194304 f32
    ushort* pHi  = (ushort*)r2;        // z-stride 4194304 ush; w aliases
    ushort* yT   = (ushort*)r3;        // z-stride 2097152 ush

    cvt_f16<<<dim3(1024, 1, 1), dim3(256), 0, stream>>>(W, W16, 0, 0);

    for (int bs = 0; bs < 16; bs += G) {
        const float* xg = x + (size_t)bs * BD;
        const float* yg = y + (size_t)bs * BD;

        cvt_f16<<<dim3(2048, 1, G), dim3(256), 0, stream>>>(
            xg, xyHi, BD / 4, 8388608);
        cvt_transpose<<<dim3(32, 64, G), dim3(256), 0, stream>>>(
            yg, xyHi + BD, yT, BD, 8388608, BD);

        // proj: M=4096, N=1024, K=1024 (T=16)
        gemm256<1><<<dim3(4, 16, G), dim3(512), 0, stream>>>(
            xyHi, 8388608, W16, 0,
            bias, nullptr, 0,
            nullptr, pHi, 4194304, 1024, 1024, 1024, 16);

        // scores: M=N=2048, K=1024 (T=16), masked
        gemm256<2><<<dim3(8, 8, G), dim3(512), 0, stream>>>(
            pHi, 4194304, pHi + BD, 4194304,
            nullptr, ymask + (size_t)bs * 2048, 2048,
            sc, nullptr, 4194304, 1024, 1024, 2048, 16);

        softmax_f16<<<dim3(G * 2048), dim3(256), 0, stream>>>(
            sc, pHi, 4194304, 4194304);

        // out: M=2048, N=1024, K=2048 (T=32)
        gemm256<0><<<dim3(4, 8, G), dim3(512), 0, stream>>>(
            pHi, 4194304, yT, 2097152,
            nullptr, nullptr, 0,
            out + (size_t)bs * BD, nullptr, BD, 2048, 2048, 1024, 32);
    }
}

// Round 10
// 512.622 us; speedup vs baseline: 1.3666x; 1.2449x over previous
//
#include <hip/hip_runtime.h>
#include <math.h>
#include <stdint.h>

// B=16, XL=YL=2048, D=1024. fp16 1-pass pipeline + MASK COMPACTION:
//   idx  : per batch, compact indices of unmasked y cols; NY, NYPAD=ceil256(NY)
//   gathr: yc[i]=y[idx[i]] fp16 rows (into xy rows 2048+) + yTc (D x NYPAD) fp16
//   proj : p = relu([x;yc]16 @ W16^T + b)  K=1024 -> pHi fp16 (y-part: NYPAD rows)
//   score: sc = xp @ ypc^T, col>=NY -> -inf N=NYPAD -> fp32
//   soft : w = softmax(sc[0:NYPAD])        -> fp16 (aliases pHi)
//   out  : out = w @ yTc^T                 K=NYPAD (runtime T) -> fp32
// Masked columns have exactly 0 weight, so compacted result == reference
// (modulo fp32 reassociation in the out-GEMM sum).
// GEMM: 256x256 tile, K-tiles of 64, 8 waves, 2 LDS buffers (128KB), unrolled
// 4-phase/tile schedule, counted vmcnt(8), pair-row XOR swizzle (0-conflict).

typedef __attribute__((ext_vector_type(8))) _Float16 f16x8;
typedef __attribute__((ext_vector_type(4))) float f32x4;

__device__ __forceinline__ ushort h2u(_Float16 h) { return __builtin_bit_cast(ushort, h); }

__device__ __forceinline__ void ld16(const ushort* g, ushort* l) {
    __builtin_amdgcn_global_load_lds(
        (__attribute__((address_space(1))) void*)(g),
        (__attribute__((address_space(3))) void*)(l), 16, 0, 0);
}

#define BAR()   { __builtin_amdgcn_s_barrier(); asm volatile("" ::: "memory"); }
#define LGKM0() { asm volatile("s_waitcnt lgkmcnt(0)" ::: "memory"); __builtin_amdgcn_sched_barrier(0); }
#define VMW(N)  asm volatile("s_waitcnt vmcnt(" #N ")" ::: "memory");

// C = A @ B^T; A,B fp16 k-contiguous. MODE 0: plain. MODE 1: proj (A-row early
// exit for y region >= NYPAD). MODE 2: scores (B-col exit >= NYPAD; epilogue
// col>=NY -> -inf). MODE 3: out (runtime T = NYPAD/64).
// EPI 0: fp32 C. EPI 1: relu(C+bias[n]) -> fp16 Chi. EPI 2: -inf mask, fp32.
template<int EPI, int MODE>
__global__ __launch_bounds__(512) void gemm256(
    const ushort* __restrict__ A, size_t zsA,
    const ushort* __restrict__ B, size_t zsB,
    const float* __restrict__ bias, const int* __restrict__ nyBuf,
    float* __restrict__ Cf, ushort* __restrict__ Chi, size_t zsC,
    int sdA, int sdB, int N, int T)
{
    __shared__ char ldsb[131072];   // A [0,64K): buf(32K){kk(16K)}, B [64K,128K)

    // XCD-aware bijective block swizzle (all grids divisible by 8)
    const int gx = gridDim.x, gxy = gx * gridDim.y;
    const int total = gxy * gridDim.z;
    int hsw = blockIdx.z * gxy + blockIdx.y * gx + blockIdx.x;
    hsw = (hsw & 7) * (total >> 3) + (hsw >> 3);
    const int z = hsw / gxy;
    const int rem = hsw - z * gxy;
    const int by = rem / gx;
    const int bx = rem - by * gx;

    int NY = 0, NYPAD = 0;
    if constexpr (MODE != 0) { NY = nyBuf[2 * z]; NYPAD = nyBuf[2 * z + 1]; }
    if constexpr (MODE == 1) { if (by * 256 >= 2048 && by * 256 - 2048 >= NYPAD) return; }
    if constexpr (MODE == 2) { if (bx * 256 >= NYPAD) return; }
    if constexpr (MODE == 3) { T = NYPAD >> 6; }

    const int tid = threadIdx.x;
    const int lane = tid & 63;
    const int wv = tid >> 6, wm = wv >> 2, wn = wv & 3;
    const int m0 = by * 256, n0 = bx * 256;

    // staging (pair-row swizzle): dest linear tid*16 within 16KB kk-region;
    // logical slot s = (tid&7)^((tid>>3)&7); row = 2*(tid>>3)+(s>>2); k=(s&3)*8
    const int pl  = tid >> 3;
    const int ss  = (tid & 7) ^ (pl & 7);
    const int sr0 = 2 * pl + (ss >> 2);
    const int ske = (ss & 3) * 8;
    const int tb  = tid * 16;

    const ushort* gA0 = A + (size_t)z * zsA + (size_t)(m0 + sr0) * sdA + ske;
    const ushort* gA1 = A + (size_t)z * zsA + (size_t)(m0 + 128 + sr0) * sdA + ske;
    const ushort* gB0 = B + (size_t)z * zsB + (size_t)(n0 + sr0) * sdB + ske;
    const ushort* gB1 = B + (size_t)z * zsB + (size_t)(n0 + 128 + sr0) * sdB + ske;

#define ST_A(KOF, DOF) { ld16(gA0 + (KOF), (ushort*)(ldsb + (DOF) + tb));          \
                         ld16(gA1 + (KOF), (ushort*)(ldsb + (DOF) + 8192 + tb)); }
#define ST_B(KOF, DOF) { ld16(gB0 + (KOF), (ushort*)(ldsb + 65536 + (DOF) + tb));  \
                         ld16(gB1 + (KOF), (ushort*)(ldsb + 65536 + (DOF) + 8192 + tb)); }

    // compute-side read addresses (same swizzle)
    const int fr = lane & 15, fq = lane >> 4;
    const int sl = (((fr & 1) << 2) | fq) ^ ((fr >> 1) & 7);
    const int aoff = (wm * 64 + (fr >> 1)) * 128 + sl * 16;
    const int boff = (wn * 32 + (fr >> 1)) * 128 + sl * 16;

    f32x4 acc[8][4];
    #pragma unroll
    for (int i = 0; i < 8; ++i)
        #pragma unroll
        for (int j = 0; j < 4; ++j)
            acc[i][j] = (f32x4){0.f, 0.f, 0.f, 0.f};

    f16x8 a[4], b[4];

#define RD_B(DOF) { const char* p_ = ldsb + 65536 + (DOF) + boff;                  \
    b[0] = *(const f16x8*)(p_);        b[1] = *(const f16x8*)(p_ + 1024);          \
    b[2] = *(const f16x8*)(p_ + 2048); b[3] = *(const f16x8*)(p_ + 3072); }
#define RD_AL(DOF) { const char* p_ = ldsb + (DOF) + aoff;                         \
    a[0] = *(const f16x8*)(p_);        a[1] = *(const f16x8*)(p_ + 1024);          \
    a[2] = *(const f16x8*)(p_ + 2048); a[3] = *(const f16x8*)(p_ + 3072); }
#define RD_AH(DOF) { const char* p_ = ldsb + (DOF) + aoff + 4096;                  \
    a[0] = *(const f16x8*)(p_);        a[1] = *(const f16x8*)(p_ + 1024);          \
    a[2] = *(const f16x8*)(p_ + 2048); a[3] = *(const f16x8*)(p_ + 3072); }
#define MF_L { __builtin_amdgcn_s_setprio(1);                                      \
    _Pragma("unroll") for (int m_ = 0; m_ < 4; ++m_)                               \
        _Pragma("unroll") for (int n_ = 0; n_ < 4; ++n_)                           \
            acc[m_][n_] = __builtin_amdgcn_mfma_f32_16x16x32_f16(a[m_], b[n_], acc[m_][n_], 0, 0, 0); \
    __builtin_amdgcn_s_setprio(0); }
#define MF_H { __builtin_amdgcn_s_setprio(1);                                      \
    _Pragma("unroll") for (int m_ = 0; m_ < 4; ++m_)                               \
        _Pragma("unroll") for (int n_ = 0; n_ < 4; ++n_)                           \
            acc[m_ + 4][n_] = __builtin_amdgcn_mfma_f32_16x16x32_f16(a[m_], b[n_], acc[m_ + 4][n_], 0, 0, 0); \
    __builtin_amdgcn_s_setprio(0); }

#define TILE(BUF, S0, S1, S2, S3, W1, W3)                                          \
    RD_B((BUF)*32768); RD_AL((BUF)*32768);                                         \
    S0; BAR(); LGKM0(); MF_L; BAR();                                               \
    RD_AH((BUF)*32768);                                                            \
    S1; BAR(); LGKM0(); MF_H; W1; BAR();                                           \
    RD_B((BUF)*32768 + 16384); RD_AL((BUF)*32768 + 16384);                         \
    S2; BAR(); LGKM0(); MF_L; BAR();                                               \
    RD_AH((BUF)*32768 + 16384);                                                    \
    S3; BAR(); LGKM0(); MF_H; W3; BAR();

    // prologue: tile0 all 4 units + tile1 kk0 units (12 loads); wait tile0-kk0
    ST_A(0, 0);      ST_B(0, 0);
    ST_A(32, 16384); ST_B(32, 16384);
    ST_A(64, 32768); ST_B(64, 32768);
    VMW(8);
    BAR();

    for (int it = 0; it < (T - 2) / 2; ++it) {
        TILE(0, ST_A(96, 49152),  ST_B(96, 49152),  ST_A(128, 0),     ST_B(128, 0),     VMW(8), VMW(8))
        TILE(1, ST_A(160, 16384), ST_B(160, 16384), ST_A(192, 32768), ST_B(192, 32768), VMW(8), VMW(8))
        gA0 += 128; gA1 += 128; gB0 += 128; gB1 += 128;
    }
    TILE(0, ST_A(96, 49152), ST_B(96, 49152), , , VMW(8), VMW(4))
    TILE(1, , , , , VMW(0), )

    // epilogue: within 16x16 frag, col = fr, row = fq*4 + r
    #pragma unroll
    for (int n = 0; n < 4; ++n) {
        const int col = n0 + wn * 64 + n * 16 + fr;
        float bb = 0.f;
        if constexpr (EPI == 1) bb = bias[col];
        #pragma unroll
        for (int m = 0; m < 8; ++m) {
            const int row = m0 + wm * 128 + m * 16 + fq * 4;
            #pragma unroll
            for (int r = 0; r < 4; ++r) {
                const float v = acc[m][n][r];
                const size_t idx = (size_t)z * zsC + (size_t)(row + r) * N + col;
                if constexpr (EPI == 0) {
                    Cf[idx] = v;
                } else if constexpr (EPI == 1) {
                    Chi[idx] = h2u((_Float16)fmaxf(v + bb, 0.f));
                } else {
                    Cf[idx] = (col >= NY) ? -INFINITY : v;
                }
            }
        }
    }
#undef ST_A
#undef ST_B
#undef RD_B
#undef RD_AL
#undef RD_AH
#undef MF_L
#undef MF_H
#undef TILE
}

// per batch: compact index list of unmasked cols + NY/NYPAD. 1 block/batch.
__global__ __launch_bounds__(256) void build_idx(const int* __restrict__ mask,
    int* __restrict__ idx, int* __restrict__ nyBuf)
{
    const int z = blockIdx.x;
    const int* mb = mask + (size_t)z * 2048;
    __shared__ int part[256];
    const int tid = threadIdx.x;
    int keep[8]; int c = 0;
    #pragma unroll
    for (int k = 0; k < 8; ++k) { keep[k] = (mb[tid * 8 + k] == 0); c += keep[k]; }
    part[tid] = c;
    for (int off = 1; off < 256; off <<= 1) {
        __syncthreads();
        const int v = (tid >= off) ? part[tid - off] : 0;
        __syncthreads();
        part[tid] += v;
    }
    __syncthreads();
    int pos = part[tid] - c;   // exclusive prefix
    #pragma unroll
    for (int k = 0; k < 8; ++k)
        if (keep[k]) idx[(size_t)z * 2048 + (pos++)] = tid * 8 + k;
    if (tid == 255) {
        const int ny = part[255];
        int nyp = (ny + 255) & ~255;
        if (nyp < 256) nyp = 256;
        nyBuf[2 * z] = ny;
        nyBuf[2 * z + 1] = nyp;
    }
}

// fp32 -> fp16, 4 elems/thread, z-batched
__global__ __launch_bounds__(256) void cvt_f16(const float* __restrict__ in,
    ushort* __restrict__ o, size_t sIn4, size_t sOut)
{
    const size_t z = blockIdx.z;
    const int i = blockIdx.x * 256 + threadIdx.x;
    const float4 v = reinterpret_cast<const float4*>(in)[z * sIn4 + i];
    ushort4 h;
    h.x = h2u((_Float16)v.x); h.y = h2u((_Float16)v.y);
    h.z = h2u((_Float16)v.z); h.w = h2u((_Float16)v.w);
    reinterpret_cast<ushort4*>(o + z * sOut)[i] = h;
}

// gather compacted y rows -> fp16 rows (rH, compact row i) + transpose (tT: 1024 x 2048)
// rows [NY, NYPAD) zero-filled; blocks beyond NYPAD exit.
__global__ __launch_bounds__(256) void gather_y(const float* __restrict__ y,
    const int* __restrict__ idx, const int* __restrict__ nyBuf,
    ushort* __restrict__ rH, ushort* __restrict__ tT,
    size_t sIn, size_t sR, size_t sT)
{
    __shared__ float tile[32][33];
    const size_t z = blockIdx.z;
    const int NY = nyBuf[2 * z], NYPAD = nyBuf[2 * z + 1];
    const int r0 = blockIdx.y * 32;
    if (r0 >= NYPAD) return;
    const int c0 = blockIdx.x * 32;
    const float* yb = y + z * sIn;
    const int* idxb = idx + z * 2048;
    const int tx = threadIdx.x & 31, ty = threadIdx.x >> 5;
    #pragma unroll
    for (int k = 0; k < 4; ++k) {
        const int i = r0 + ty + k * 8;
        float v = 0.f;
        if (i < NY) v = yb[(size_t)idxb[i] * 1024 + c0 + tx];
        tile[ty + k * 8][tx] = v;
        rH[z * sR + (size_t)i * 1024 + c0 + tx] = h2u((_Float16)v);
    }
    __syncthreads();
    #pragma unroll
    for (int k = 0; k < 4; ++k) {
        const int c = c0 + ty + k * 8;
        tT[z * sT + (size_t)c * 2048 + r0 + tx] = h2u((_Float16)tile[tx][ty + k * 8]);
    }
}

// row softmax over NYPAD cols -> fp16; grid.x = G*2048 rows
__global__ __launch_bounds__(256) void softmax_f16(const float* __restrict__ S,
    ushort* __restrict__ Wout, const int* __restrict__ nyBuf, size_t sS, size_t sW)
{
    const size_t row = blockIdx.x;
    const size_t b = row >> 11, r = row & 2047;
    const int nf4 = nyBuf[2 * b + 1] >> 2;   // NYPAD / 4
    const float4* p4 = reinterpret_cast<const float4*>(S + b * sS + r * 2048);
    ushort4* q4 = reinterpret_cast<ushort4*>(Wout + b * sW + r * 2048);
    const int tid = threadIdx.x;

    const float4 NEG = {-INFINITY, -INFINITY, -INFINITY, -INFINITY};
    float4 v0 = (tid < nf4) ? p4[tid] : NEG;
    float4 v1 = (tid + 256 < nf4) ? p4[tid + 256] : NEG;
    float m = fmaxf(fmaxf(fmaxf(v0.x, v0.y), fmaxf(v0.z, v0.w)),
                    fmaxf(fmaxf(v1.x, v1.y), fmaxf(v1.z, v1.w)));
    #pragma unroll
    for (int off = 32; off >= 1; off >>= 1)
        m = fmaxf(m, __shfl_xor(m, off));

    __shared__ float redm[4], reds[4];
    if ((tid & 63) == 0) redm[tid >> 6] = m;
    __syncthreads();
    m = fmaxf(fmaxf(redm[0], redm[1]), fmaxf(redm[2], redm[3]));

    float e[8];
    e[0] = __expf(v0.x - m); e[1] = __expf(v0.y - m);
    e[2] = __expf(v0.z - m); e[3] = __expf(v0.w - m);
    e[4] = __expf(v1.x - m); e[5] = __expf(v1.y - m);
    e[6] = __expf(v1.z - m); e[7] = __expf(v1.w - m);
    float s = ((e[0] + e[1]) + (e[2] + e[3])) + ((e[4] + e[5]) + (e[6] + e[7]));
    #pragma unroll
    for (int off = 32; off >= 1; off >>= 1)
        s += __shfl_xor(s, off);
    if ((tid & 63) == 0) reds[tid >> 6] = s;
    __syncthreads();
    s = reds[0] + reds[1] + reds[2] + reds[3];

    const float inv = 1.f / s;
    ushort4 o0, o1;
    o0.x = h2u((_Float16)(e[0] * inv)); o0.y = h2u((_Float16)(e[1] * inv));
    o0.z = h2u((_Float16)(e[2] * inv)); o0.w = h2u((_Float16)(e[3] * inv));
    o1.x = h2u((_Float16)(e[4] * inv)); o1.y = h2u((_Float16)(e[5] * inv));
    o1.z = h2u((_Float16)(e[6] * inv)); o1.w = h2u((_Float16)(e[7] * inv));
    if (tid < nf4) q4[tid] = o0;
    if (tid + 256 < nf4) q4[tid + 256] = o1;
}

extern "C" void kernel_launch(void* const* d_in, const int* in_sizes, int n_in,
                              void* d_out, int out_size, void* d_ws, size_t ws_size,
                              hipStream_t stream)
{
    const float* x    = (const float*)d_in[0];  // (16, 2048, 1024)
    const float* y    = (const float*)d_in[1];  // (16, 2048, 1024)
    const int* ymask  = (const int*)d_in[2];    // (16, 2048)
    const float* W    = (const float*)d_in[3];  // (1024, 1024)
    const float* bias = (const float*)d_in[4];  // (1024,)
    float* out = (float*)d_out;

    const size_t BD = 2097152;                  // 2048*1024

    // hdr 4MB: W16 2MB | idx 128KB | nyBuf
    // per batch: R1 16MB (xy fp16 8MB; sc fp32 aliases) | R2 8MB p/w | R3 4MB yTc
    const size_t perBatch = 29360128ull;
    int G = 16;
    while (G > 1 && 4194304ull + (size_t)G * perBatch > ws_size) G >>= 1;

    uint8_t* wsb = (uint8_t*)d_ws;
    ushort* W16  = (ushort*)wsb;                         // 2 MB
    int* idxBuf  = (int*)(wsb + 2097152);                // 128 KB
    int* nyBuf   = (int*)(wsb + 2097152 + 131072);       // 128 B
    uint8_t* r1  = wsb + 4194304;                        // G * 16MB
    uint8_t* r2  = r1 + (size_t)G * 16777216;            // G * 8MB
    uint8_t* r3  = r2 + (size_t)G * 8388608;             // G * 4MB

    ushort* xyHi = (ushort*)r1;        // z-stride 8388608 ush
    float*  sc   = (float*)r1;         // z-stride 4194304 f32
    ushort* pHi  = (ushort*)r2;        // z-stride 4194304 ush; w aliases
    ushort* yT   = (ushort*)r3;        // z-stride 2097152 ush (D x 2048 compact)

    cvt_f16<<<dim3(1024, 1, 1), dim3(256), 0, stream>>>(W, W16, 0, 0);
    build_idx<<<dim3(16), dim3(256), 0, stream>>>(ymask, idxBuf, nyBuf);

    for (int bs = 0; bs < 16; bs += G) {
        const float* xg = x + (size_t)bs * BD;
        const float* yg = y + (size_t)bs * BD;
        const int* nyB  = nyBuf + 2 * bs;

        // x -> xy rows [0,2048) fp16
        cvt_f16<<<dim3(2048, 1, G), dim3(256), 0, stream>>>(
            xg, xyHi, BD / 4, 8388608);
        // compacted y -> xy rows [2048, 2048+NYPAD) fp16 + yTc fp16
        gather_y<<<dim3(32, 64, G), dim3(256), 0, stream>>>(
            yg, idxBuf + (size_t)bs * 2048, nyB,
            xyHi + BD, yT, BD, 8388608, BD);

        // proj: M=2048+NYPAD, N=1024, K=1024 (T=16); grid covers 4096 rows
        gemm256<1, 1><<<dim3(4, 16, G), dim3(512), 0, stream>>>(
            xyHi, 8388608, W16, 0,
            bias, nyB,
            nullptr, pHi, 4194304, 1024, 1024, 1024, 16);

        // scores: M=2048, N=NYPAD (early exit), K=1024; col>=NY -> -inf
        gemm256<2, 2><<<dim3(8, 8, G), dim3(512), 0, stream>>>(
            pHi, 4194304, pHi + BD, 4194304,
            nullptr, nyB,
            sc, nullptr, 4194304, 1024, 1024, 2048, 16);

        // softmax over NYPAD cols -> w (aliases pHi)
        softmax_f16<<<dim3(G * 2048), dim3(256), 0, stream>>>(
            sc, pHi, nyB, 4194304, 4194304);

        // out: M=2048, N=1024, K=NYPAD (runtime T)
        gemm256<0, 3><<<dim3(4, 8, G), dim3(512), 0, stream>>>(
            pHi, 4194304, yT, 2097152,
            nullptr, nyB,
            out + (size_t)bs * BD, nullptr, BD, 2048, 2048, 1024, 32);
    }
}

// Round 11
// 503.409 us; speedup vs baseline: 1.3917x; 1.0183x over previous
//
#include <hip/hip_runtime.h>
#include <math.h>
#include <stdint.h>

// B=16, XL=YL=2048, D=1024. fp16 1-pass pipeline + mask compaction (NYPAD ceil128):
//   idx/gather: compact unmasked y cols; yc fp16 rows + yTc (D x NYPAD) fp16
//   proj : p = relu([x;yc]16 @ W16^T + b)  K=1024 -> pHi fp16
//   score: sc = xp @ ypc^T, col>=NY -> -inf, N=NYPAD -> fp32
//   soft : w = softmax over NYPAD cols -> fp16 (aliases pHi; pad cols = 0)
//   out  : out = w @ yTc^T, K=NYPAD (runtime T) -> fp32
// GEMM: 256x256 tile, 64-K tiles, 8 waves, 2 LDS buffers (128KB), 4-phase/tile
// schedule with FRAGMENT DOUBLE-BUFFERING: phase p issues ds_reads for p+1,
// counted lgkmcnt(4/8) before MFMA(p) (DS completes in-order) -> MFMA overlaps
// LDS reads. vmcnt(6) after ph0/ph2 fences the one-phase-earlier reads
// (re-derived against staging-unit order; overwrite hazards unchanged).
// Pair-row XOR swizzle LDS layout (measured 0-conflict).

typedef __attribute__((ext_vector_type(8))) _Float16 f16x8;
typedef __attribute__((ext_vector_type(4))) float f32x4;

__device__ __forceinline__ ushort h2u(_Float16 h) { return __builtin_bit_cast(ushort, h); }

__device__ __forceinline__ void ld16(const ushort* g, ushort* l) {
    __builtin_amdgcn_global_load_lds(
        (__attribute__((address_space(1))) void*)(g),
        (__attribute__((address_space(3))) void*)(l), 16, 0, 0);
}

#define BAR()  { __builtin_amdgcn_s_barrier(); asm volatile("" ::: "memory"); }
#define VMW(N) asm volatile("s_waitcnt vmcnt(" #N ")" ::: "memory");
#define LG(N)  { asm volatile("s_waitcnt lgkmcnt(" #N ")" ::: "memory"); __builtin_amdgcn_sched_barrier(0); }

// C = A @ B^T; A,B fp16 k-contiguous. MODE 0: plain. MODE 1: proj (A-row early
// exit >= 2048+NYPAD). MODE 2: scores (B-col exit >= NYPAD; col>=NY -> -inf).
// MODE 3: out (runtime T = NYPAD/64).
// EPI 0: fp32 C. EPI 1: relu(C+bias[n]) -> fp16 Chi. EPI 2: -inf mask, fp32.
template<int EPI, int MODE>
__global__ __launch_bounds__(512) void gemm256(
    const ushort* __restrict__ A, size_t zsA,
    const ushort* __restrict__ B, size_t zsB,
    const float* __restrict__ bias, const int* __restrict__ nyBuf,
    float* __restrict__ Cf, ushort* __restrict__ Chi, size_t zsC,
    int sdA, int sdB, int N, int T)
{
    __shared__ char ldsb[131072];   // A [0,64K): buf(32K){kk(16K)}, B [64K,128K)

    // XCD-aware bijective block swizzle (all grids divisible by 8)
    const int gx = gridDim.x, gxy = gx * gridDim.y;
    const int total = gxy * gridDim.z;
    int hsw = blockIdx.z * gxy + blockIdx.y * gx + blockIdx.x;
    hsw = (hsw & 7) * (total >> 3) + (hsw >> 3);
    const int z = hsw / gxy;
    const int rem = hsw - z * gxy;
    const int by = rem / gx;
    const int bx = rem - by * gx;

    int NY = 0, NYPAD = 0;
    if constexpr (MODE != 0) { NY = nyBuf[2 * z]; NYPAD = nyBuf[2 * z + 1]; }
    if constexpr (MODE == 1) { if (by * 256 >= 2048 && by * 256 - 2048 >= NYPAD) return; }
    if constexpr (MODE == 2) { if (bx * 256 >= NYPAD) return; }
    if constexpr (MODE == 3) { T = NYPAD >> 6; }

    const int tid = threadIdx.x;
    const int lane = tid & 63;
    const int wv = tid >> 6, wm = wv >> 2, wn = wv & 3;
    const int m0 = by * 256, n0 = bx * 256;

    // staging (pair-row swizzle): dest linear tid*16 within 16KB kk-region;
    // logical slot s = (tid&7)^((tid>>3)&7); row = 2*(tid>>3)+(s>>2); k=(s&3)*8
    const int pl  = tid >> 3;
    const int ss  = (tid & 7) ^ (pl & 7);
    const int sr0 = 2 * pl + (ss >> 2);
    const int ske = (ss & 3) * 8;
    const int tb  = tid * 16;

    const ushort* gA0 = A + (size_t)z * zsA + (size_t)(m0 + sr0) * sdA + ske;
    const ushort* gA1 = A + (size_t)z * zsA + (size_t)(m0 + 128 + sr0) * sdA + ske;
    const ushort* gB0 = B + (size_t)z * zsB + (size_t)(n0 + sr0) * sdB + ske;
    const ushort* gB1 = B + (size_t)z * zsB + (size_t)(n0 + 128 + sr0) * sdB + ske;

#define ST_A(KOF, DOF) { ld16(gA0 + (KOF), (ushort*)(ldsb + (DOF) + tb));          \
                         ld16(gA1 + (KOF), (ushort*)(ldsb + (DOF) + 8192 + tb)); }
#define ST_B(KOF, DOF) { ld16(gB0 + (KOF), (ushort*)(ldsb + 65536 + (DOF) + tb));  \
                         ld16(gB1 + (KOF), (ushort*)(ldsb + 65536 + (DOF) + 8192 + tb)); }

    // compute-side read addresses (same swizzle)
    const int fr = lane & 15, fq = lane >> 4;
    const int sl = (((fr & 1) << 2) | fq) ^ ((fr >> 1) & 7);
    const int aoff = (wm * 64 + (fr >> 1)) * 128 + sl * 16;
    const int boff = (wn * 32 + (fr >> 1)) * 128 + sl * 16;

    f32x4 acc[8][4];
    #pragma unroll
    for (int i = 0; i < 8; ++i)
        #pragma unroll
        for (int j = 0; j < 4; ++j)
            acc[i][j] = (f32x4){0.f, 0.f, 0.f, 0.f};

    // fragment double-buffer: a0 = current L-frags, a1 = current H-frags,
    // bb0 = kk0 B-frags, bb1 = kk1 B-frags (fixed roles, no parity flip)
    f16x8 a0[4], a1[4], bb0[4], bb1[4];

#define RD4(DST, BASE) { const char* p_ = (BASE);                                  \
    DST[0] = *(const f16x8*)(p_);        DST[1] = *(const f16x8*)(p_ + 1024);      \
    DST[2] = *(const f16x8*)(p_ + 2048); DST[3] = *(const f16x8*)(p_ + 3072); }
#define MFL(AV, BV) { __builtin_amdgcn_s_setprio(1);                               \
    _Pragma("unroll") for (int m_ = 0; m_ < 4; ++m_)                               \
        _Pragma("unroll") for (int n_ = 0; n_ < 4; ++n_)                           \
            acc[m_][n_] = __builtin_amdgcn_mfma_f32_16x16x32_f16(AV[m_], BV[n_], acc[m_][n_], 0, 0, 0); \
    __builtin_amdgcn_s_setprio(0); }
#define MFH(AV, BV) { __builtin_amdgcn_s_setprio(1);                               \
    _Pragma("unroll") for (int m_ = 0; m_ < 4; ++m_)                               \
        _Pragma("unroll") for (int n_ = 0; n_ < 4; ++n_)                           \
            acc[m_ + 4][n_] = __builtin_amdgcn_mfma_f32_16x16x32_f16(AV[m_], BV[n_], acc[m_ + 4][n_], 0, 0, 0); \
    __builtin_amdgcn_s_setprio(0); }

// 4 phases/tile; reads issued one phase ahead of use.
// D0/D1 = this tile's kk0/kk1 DOF; DN = next tile's kk0 DOF.
#define TILE(D0, D1, DN, S0, S1, S2, S3, V0, V2)                                   \
    RD4(a1, ldsb + (D0) + aoff + 4096);                                            \
    S0; BAR(); LG(4); MFL(a0, bb0); V0; BAR();                                     \
    RD4(bb1, ldsb + 65536 + (D1) + boff); RD4(a0, ldsb + (D1) + aoff);             \
    S1; BAR(); LG(8); MFH(a1, bb0); BAR();                                         \
    RD4(a1, ldsb + (D1) + aoff + 4096);                                            \
    S2; BAR(); LG(4); MFL(a0, bb1); V2; BAR();                                     \
    RD4(bb0, ldsb + 65536 + (DN) + boff); RD4(a0, ldsb + (DN) + aoff);             \
    S3; BAR(); LG(8); MFH(a1, bb1); BAR();

    // prologue: stage (0,kk0),(0,kk1),(1,kk0); wait (0,kk0); pre-read kk0 frags
    ST_A(0, 0);      ST_B(0, 0);
    ST_A(32, 16384); ST_B(32, 16384);
    ST_A(64, 32768); ST_B(64, 32768);
    VMW(8);
    BAR();
    RD4(bb0, ldsb + 65536 + boff);
    RD4(a0, ldsb + aoff);

    for (int it = 0; it < (T - 2) / 2; ++it) {
        TILE(0, 16384, 32768,
             ST_A(96, 49152), ST_B(96, 49152), ST_A(128, 0), ST_B(128, 0),
             VMW(6), VMW(6))
        TILE(32768, 49152, 0,
             ST_A(160, 16384), ST_B(160, 16384), ST_A(192, 32768), ST_B(192, 32768),
             VMW(6), VMW(6))
        gA0 += 128; gA1 += 128; gB0 += 128; gB1 += 128;
    }
    // tail: tile T-2 (stages (T-1,kk1) only), tile T-1 (drain; DN reads dummy)
    TILE(0, 16384, 32768, ST_A(96, 49152), ST_B(96, 49152), , , VMW(6), VMW(4))
    TILE(32768, 49152, 32768, , , , , VMW(0), )

    // epilogue: within 16x16 frag, col = fr, row = fq*4 + r
    #pragma unroll
    for (int n = 0; n < 4; ++n) {
        const int col = n0 + wn * 64 + n * 16 + fr;
        float bb = 0.f;
        if constexpr (EPI == 1) bb = bias[col];
        #pragma unroll
        for (int m = 0; m < 8; ++m) {
            const int row = m0 + wm * 128 + m * 16 + fq * 4;
            #pragma unroll
            for (int r = 0; r < 4; ++r) {
                const float v = acc[m][n][r];
                const size_t idx = (size_t)z * zsC + (size_t)(row + r) * N + col;
                if constexpr (EPI == 0) {
                    Cf[idx] = v;
                } else if constexpr (EPI == 1) {
                    Chi[idx] = h2u((_Float16)fmaxf(v + bb, 0.f));
                } else {
                    Cf[idx] = (col >= NY) ? -INFINITY : v;
                }
            }
        }
    }
#undef ST_A
#undef ST_B
#undef RD4
#undef MFL
#undef MFH
#undef TILE
}

// per batch: compact index list of unmasked cols + NY/NYPAD (ceil128, min 256)
__global__ __launch_bounds__(256) void build_idx(const int* __restrict__ mask,
    int* __restrict__ idx, int* __restrict__ nyBuf)
{
    const int z = blockIdx.x;
    const int* mb = mask + (size_t)z * 2048;
    __shared__ int part[256];
    const int tid = threadIdx.x;
    int keep[8]; int c = 0;
    #pragma unroll
    for (int k = 0; k < 8; ++k) { keep[k] = (mb[tid * 8 + k] == 0); c += keep[k]; }
    part[tid] = c;
    for (int off = 1; off < 256; off <<= 1) {
        __syncthreads();
        const int v = (tid >= off) ? part[tid - off] : 0;
        __syncthreads();
        part[tid] += v;
    }
    __syncthreads();
    int pos = part[tid] - c;   // exclusive prefix
    #pragma unroll
    for (int k = 0; k < 8; ++k)
        if (keep[k]) idx[(size_t)z * 2048 + (pos++)] = tid * 8 + k;
    if (tid == 255) {
        const int ny = part[255];
        int nyp = (ny + 127) & ~127;
        if (nyp < 256) nyp = 256;
        nyBuf[2 * z] = ny;
        nyBuf[2 * z + 1] = nyp;
    }
}

// fp32 -> fp16, 4 elems/thread, z-batched
__global__ __launch_bounds__(256) void cvt_f16(const float* __restrict__ in,
    ushort* __restrict__ o, size_t sIn4, size_t sOut)
{
    const size_t z = blockIdx.z;
    const int i = blockIdx.x * 256 + threadIdx.x;
    const float4 v = reinterpret_cast<const float4*>(in)[z * sIn4 + i];
    ushort4 h;
    h.x = h2u((_Float16)v.x); h.y = h2u((_Float16)v.y);
    h.z = h2u((_Float16)v.z); h.w = h2u((_Float16)v.w);
    reinterpret_cast<ushort4*>(o + z * sOut)[i] = h;
}

// gather compacted y rows -> fp16 rows + transpose (1024 x 2048); pad rows zero
__global__ __launch_bounds__(256) void gather_y(const float* __restrict__ y,
    const int* __restrict__ idx, const int* __restrict__ nyBuf,
    ushort* __restrict__ rH, ushort* __restrict__ tT,
    size_t sIn, size_t sR, size_t sT)
{
    __shared__ float tile[32][33];
    const size_t z = blockIdx.z;
    const int NY = nyBuf[2 * z], NYPAD = nyBuf[2 * z + 1];
    const int r0 = blockIdx.y * 32;
    if (r0 >= NYPAD) return;
    const int c0 = blockIdx.x * 32;
    const float* yb = y + z * sIn;
    const int* idxb = idx + z * 2048;
    const int tx = threadIdx.x & 31, ty = threadIdx.x >> 5;
    #pragma unroll
    for (int k = 0; k < 4; ++k) {
        const int i = r0 + ty + k * 8;
        float v = 0.f;
        if (i < NY) v = yb[(size_t)idxb[i] * 1024 + c0 + tx];
        tile[ty + k * 8][tx] = v;
        rH[z * sR + (size_t)i * 1024 + c0 + tx] = h2u((_Float16)v);
    }
    __syncthreads();
    #pragma unroll
    for (int k = 0; k < 4; ++k) {
        const int c = c0 + ty + k * 8;
        tT[z * sT + (size_t)c * 2048 + r0 + tx] = h2u((_Float16)tile[tx][ty + k * 8]);
    }
}

// row softmax over NYPAD cols -> fp16; grid.x = G*2048 rows
__global__ __launch_bounds__(256) void softmax_f16(const float* __restrict__ S,
    ushort* __restrict__ Wout, const int* __restrict__ nyBuf, size_t sS, size_t sW)
{
    const size_t row = blockIdx.x;
    const size_t b = row >> 11, r = row & 2047;
    const int nf4 = nyBuf[2 * b + 1] >> 2;   // NYPAD / 4
    const float4* p4 = reinterpret_cast<const float4*>(S + b * sS + r * 2048);
    ushort4* q4 = reinterpret_cast<ushort4*>(Wout + b * sW + r * 2048);
    const int tid = threadIdx.x;

    const float4 NEG = {-INFINITY, -INFINITY, -INFINITY, -INFINITY};
    float4 v0 = (tid < nf4) ? p4[tid] : NEG;
    float4 v1 = (tid + 256 < nf4) ? p4[tid + 256] : NEG;
    float m = fmaxf(fmaxf(fmaxf(v0.x, v0.y), fmaxf(v0.z, v0.w)),
                    fmaxf(fmaxf(v1.x, v1.y), fmaxf(v1.z, v1.w)));
    #pragma unroll
    for (int off = 32; off >= 1; off >>= 1)
        m = fmaxf(m, __shfl_xor(m, off));

    __shared__ float redm[4], reds[4];
    if ((tid & 63) == 0) redm[tid >> 6] = m;
    __syncthreads();
    m = fmaxf(fmaxf(redm[0], redm[1]), fmaxf(redm[2], redm[3]));

    float e[8];
    e[0] = __expf(v0.x - m); e[1] = __expf(v0.y - m);
    e[2] = __expf(v0.z - m); e[3] = __expf(v0.w - m);
    e[4] = __expf(v1.x - m); e[5] = __expf(v1.y - m);
    e[6] = __expf(v1.z - m); e[7] = __expf(v1.w - m);
    float s = ((e[0] + e[1]) + (e[2] + e[3])) + ((e[4] + e[5]) + (e[6] + e[7]));
    #pragma unroll
    for (int off = 32; off >= 1; off >>= 1)
        s += __shfl_xor(s, off);
    if ((tid & 63) == 0) reds[tid >> 6] = s;
    __syncthreads();
    s = reds[0] + reds[1] + reds[2] + reds[3];

    const float inv = 1.f / s;
    ushort4 o0, o1;
    o0.x = h2u((_Float16)(e[0] * inv)); o0.y = h2u((_Float16)(e[1] * inv));
    o0.z = h2u((_Float16)(e[2] * inv)); o0.w = h2u((_Float16)(e[3] * inv));
    o1.x = h2u((_Float16)(e[4] * inv)); o1.y = h2u((_Float16)(e[5] * inv));
    o1.z = h2u((_Float16)(e[6] * inv)); o1.w = h2u((_Float16)(e[7] * inv));
    if (tid < nf4) q4[tid] = o0;
    if (tid + 256 < nf4) q4[tid + 256] = o1;
}

extern "C" void kernel_launch(void* const* d_in, const int* in_sizes, int n_in,
                              void* d_out, int out_size, void* d_ws, size_t ws_size,
                              hipStream_t stream)
{
    const float* x    = (const float*)d_in[0];  // (16, 2048, 1024)
    const float* y    = (const float*)d_in[1];  // (16, 2048, 1024)
    const int* ymask  = (const int*)d_in[2];    // (16, 2048)
    const float* W    = (const float*)d_in[3];  // (1024, 1024)
    const float* bias = (const float*)d_in[4];  // (1024,)
    float* out = (float*)d_out;

    const size_t BD = 2097152;                  // 2048*1024

    // hdr 4MB: W16 2MB | idx 128KB | nyBuf
    // per batch: R1 16MB (xy fp16 8MB; sc fp32 aliases) | R2 8MB p/w | R3 4MB yTc
    const size_t perBatch = 29360128ull;
    int G = 16;
    while (G > 1 && 4194304ull + (size_t)G * perBatch > ws_size) G >>= 1;

    uint8_t* wsb = (uint8_t*)d_ws;
    ushort* W16  = (ushort*)wsb;                         // 2 MB
    int* idxBuf  = (int*)(wsb + 2097152);                // 128 KB
    int* nyBuf   = (int*)(wsb + 2097152 + 131072);       // 128 B
    uint8_t* r1  = wsb + 4194304;                        // G * 16MB
    uint8_t* r2  = r1 + (size_t)G * 16777216;            // G * 8MB
    uint8_t* r3  = r2 + (size_t)G * 8388608;             // G * 4MB

    ushort* xyHi = (ushort*)r1;        // z-stride 8388608 ush
    float*  sc   = (float*)r1;         // z-stride 4194304 f32
    ushort* pHi  = (ushort*)r2;        // z-stride 4194304 ush; w aliases
    ushort* yT   = (ushort*)r3;        // z-stride 2097152 ush (D x 2048 compact)

    cvt_f16<<<dim3(1024, 1, 1), dim3(256), 0, stream>>>(W, W16, 0, 0);
    build_idx<<<dim3(16), dim3(256), 0, stream>>>(ymask, idxBuf, nyBuf);

    for (int bs = 0; bs < 16; bs += G) {
        const float* xg = x + (size_t)bs * BD;
        const float* yg = y + (size_t)bs * BD;
        const int* nyB  = nyBuf + 2 * bs;

        // x -> xy rows [0,2048) fp16
        cvt_f16<<<dim3(2048, 1, G), dim3(256), 0, stream>>>(
            xg, xyHi, BD / 4, 8388608);
        // compacted y -> xy rows [2048, 2048+NYPAD) fp16 + yTc fp16
        gather_y<<<dim3(32, 64, G), dim3(256), 0, stream>>>(
            yg, idxBuf + (size_t)bs * 2048, nyB,
            xyHi + BD, yT, BD, 8388608, BD);

        // proj: M=2048+NYPAD (early exit), N=1024, K=1024 (T=16)
        gemm256<1, 1><<<dim3(4, 16, G), dim3(512), 0, stream>>>(
            xyHi, 8388608, W16, 0,
            bias, nyB,
            nullptr, pHi, 4194304, 1024, 1024, 1024, 16);

        // scores: M=2048, N=NYPAD (early exit), K=1024; col>=NY -> -inf
        gemm256<2, 2><<<dim3(8, 8, G), dim3(512), 0, stream>>>(
            pHi, 4194304, pHi + BD, 4194304,
            nullptr, nyB,
            sc, nullptr, 4194304, 1024, 1024, 2048, 16);

        // softmax over NYPAD cols -> w (aliases pHi)
        softmax_f16<<<dim3(G * 2048), dim3(256), 0, stream>>>(
            sc, pHi, nyB, 4194304, 4194304);

        // out: M=2048, N=1024, K=NYPAD (runtime T)
        gemm256<0, 3><<<dim3(4, 8, G), dim3(512), 0, stream>>>(
            pHi, 4194304, yT, 2097152,
            nullptr, nyB,
            out + (size_t)bs * BD, nullptr, BD, 2048, 2048, 1024, 32);
    }
}